// Round 6
// baseline (596.420 us; speedup 1.0000x reference)
//
#include <hip/hip_runtime.h>
#include <hip/hip_fp16.h>

#define N_NODES 100000
#define N_EDGES 1250000
#define DIM 64
#define EDGE_DIM 10
#define BN_EPS 1e-5f

// workspace layout (bytes):
//   aggr2 : N_NODES*64 halves            = 12,800,000 B   (zeroed each call)
//   sums  : 256 floats                   = 1,024 B        (zeroed each call)
//   xh    : N_NODES*64 halves            = 12,800,000 B
#define AGGR_BYTES (N_NODES * DIM * 2)
#define SUMS_BYTES 1024

// -----------------------------------------------------------------------------
// prep: x (fp32) -> xh (fp16), 2 elems/thread
// -----------------------------------------------------------------------------
extern "C" __global__ __launch_bounds__(256)
void prep_kernel(const float* __restrict__ x, __half2* __restrict__ xh2)
{
    int i = blockIdx.x * 256 + threadIdx.x;   // < 3.2M
    float2 v = ((const float2*)x)[i];
    xh2[i] = __floats2half2_rn(v.x, v.y);
}

// -----------------------------------------------------------------------------
// edge kernel: thread = (edge, feature-pair). 32 threads per edge.
// msg = ReLU(x[src] + ea@We + be); packed-f16 atomic add into aggr[dst].
// 40M pk atomics (1 per 2 features) vs 80M scalar: op-rate and line-traffic x0.5.
// -----------------------------------------------------------------------------
extern "C" __global__ __launch_bounds__(256)
void edge_kernel(const int* __restrict__ ei,
                 const float* __restrict__ ea,
                 const float* __restrict__ We,
                 const float* __restrict__ be,
                 const __half2* __restrict__ xh2,
                 __half2* __restrict__ aggr2)
{
    int t  = blockIdx.x * 256 + threadIdx.x;   // < 40M
    int e  = t >> 5;
    int fp = t & 31;

    unsigned src = (unsigned)ei[e];
    unsigned dst = (unsigned)ei[N_EDGES + e];
    src = src < N_NODES ? src : (N_NODES - 1);
    dst = dst < N_NODES ? dst : (N_NODES - 1);

    const float2* We2 = (const float2*)We;
    float2 b = ((const float2*)be)[fp];
    float m0 = b.x, m1 = b.y;
    #pragma unroll
    for (int k = 0; k < EDGE_DIM; ++k) {
        float a = ea[e * EDGE_DIM + k];          // broadcast across 32 lanes
        float2 w = We2[k * 32 + fp];             // coalesced, L1-resident
        m0 = fmaf(a, w.x, m0);
        m1 = fmaf(a, w.y, m1);
    }
    float2 xv = __half22float2(xh2[src * 32 + fp]);  // 128 B/edge random line
    m0 = fmaxf(m0 + xv.x, 0.0f);
    m1 = fmaxf(m1 + xv.y, 0.0f);
    unsafeAtomicAdd(&aggr2[dst * 32 + fp], __floats2half2_rn(m0, m1));
}

// -----------------------------------------------------------------------------
// node kernel: 64-node tile, 512 threads. h = x + aggr (streaming);
// T = ReLU(h@W1+b1); R = ReLU(T@W2+b2) -> out; BN partial sums.
// -----------------------------------------------------------------------------
extern "C" __global__ __launch_bounds__(512)
void node_kernel(const float* __restrict__ x,
                 const __half2* __restrict__ aggr2,
                 const float* __restrict__ W1,
                 const float* __restrict__ b1,
                 const float* __restrict__ W2,
                 const float* __restrict__ b2,
                 float* __restrict__ out,
                 float* __restrict__ sums)
{
    __shared__ __align__(16) float sW1[DIM * DIM];
    __shared__ __align__(16) float sW2[DIM * DIM];
    __shared__ __align__(16) float sT[DIM * 68];   // [feat][node], pad 68

    int tid  = threadIdx.x;
    int base = blockIdx.x * 64;

    for (int i = tid; i < DIM * DIM; i += 512) {
        sW1[i] = W1[i];
        sW2[i] = W2[i];
    }

    // load H = x + aggr, store transposed into sT
    #pragma unroll
    for (int it = 0; it < 2; ++it) {
        int flat4 = it * 512 + tid;      // float4 index within 64x64 tile
        int node  = flat4 >> 4;
        int f0    = (flat4 & 15) * 4;
        int n     = base + node;
        float4 h4 = make_float4(0.f, 0.f, 0.f, 0.f);
        if (n < N_NODES) {
            float4 xv = *(const float4*)&x[(size_t)n * DIM + f0];
            float2 a0 = __half22float2(aggr2[n * 32 + (f0 >> 1)]);
            float2 a1 = __half22float2(aggr2[n * 32 + (f0 >> 1) + 1]);
            h4 = make_float4(xv.x + a0.x, xv.y + a0.y, xv.z + a1.x, xv.w + a1.y);
        }
        sT[(f0 + 0) * 68 + node] = h4.x;
        sT[(f0 + 1) * 68 + node] = h4.y;
        sT[(f0 + 2) * 68 + node] = h4.z;
        sT[(f0 + 3) * 68 + node] = h4.w;
    }
    __syncthreads();

    int i0 = (tid & 15) * 4;   // node offset
    int j0 = (tid >> 4) * 2;   // feature offset

    float acc1[4][2] = {};
    #pragma unroll 8
    for (int k = 0; k < DIM; ++k) {
        float4 av = *(const float4*)&sT[k * 68 + i0];
        float bw0 = sW1[k * DIM + j0];
        float bw1 = sW1[k * DIM + j0 + 1];
        float a4[4] = {av.x, av.y, av.z, av.w};
        #pragma unroll
        for (int a = 0; a < 4; ++a) {
            acc1[a][0] = fmaf(a4[a], bw0, acc1[a][0]);
            acc1[a][1] = fmaf(a4[a], bw1, acc1[a][1]);
        }
    }
    __syncthreads();

    float b1a[2] = {b1[j0], b1[j0 + 1]};
    float tv[4][2];
    #pragma unroll
    for (int a = 0; a < 4; ++a)
        #pragma unroll
        for (int b = 0; b < 2; ++b)
            tv[a][b] = fmaxf(acc1[a][b] + b1a[b], 0.0f);

    #pragma unroll
    for (int b = 0; b < 2; ++b) {
        float4 w = make_float4(tv[0][b], tv[1][b], tv[2][b], tv[3][b]);
        *(float4*)&sT[(j0 + b) * 68 + i0] = w;
    }
    __syncthreads();

    float acc2[4][2] = {};
    #pragma unroll 8
    for (int k = 0; k < DIM; ++k) {
        float4 av = *(const float4*)&sT[k * 68 + i0];
        float bw0 = sW2[k * DIM + j0];
        float bw1 = sW2[k * DIM + j0 + 1];
        float a4[4] = {av.x, av.y, av.z, av.w};
        #pragma unroll
        for (int a = 0; a < 4; ++a) {
            acc2[a][0] = fmaf(a4[a], bw0, acc2[a][0]);
            acc2[a][1] = fmaf(a4[a], bw1, acc2[a][1]);
        }
    }

    float b2a[2] = {b2[j0], b2[j0 + 1]};
    float ps[2] = {0.f, 0.f};
    float pq[2] = {0.f, 0.f};
    #pragma unroll
    for (int a = 0; a < 4; ++a) {
        int n = base + i0 + a;
        float r0 = fmaxf(acc2[a][0] + b2a[0], 0.0f);
        float r1 = fmaxf(acc2[a][1] + b2a[1], 0.0f);
        if (n < N_NODES) {
            float2 w = make_float2(r0, r1);
            *(float2*)&out[(size_t)n * DIM + j0] = w;
            ps[0] += r0; ps[1] += r1;
            pq[0] += r0 * r0; pq[1] += r1 * r1;
        }
    }

    #pragma unroll
    for (int m = 1; m < 16; m <<= 1) {
        #pragma unroll
        for (int b = 0; b < 2; ++b) {
            ps[b] += __shfl_xor(ps[b], m, 64);
            pq[b] += __shfl_xor(pq[b], m, 64);
        }
    }
    if ((tid & 15) == 0) {
        #pragma unroll
        for (int b = 0; b < 2; ++b) {
            unsafeAtomicAdd(&sums[j0 + b], ps[b]);
            unsafeAtomicAdd(&sums[64 + j0 + b], pq[b]);
        }
    }
}

// -----------------------------------------------------------------------------
// BN stats + apply
// -----------------------------------------------------------------------------
extern "C" __global__ void bn_stats_kernel(float* __restrict__ sums,
                                           const float* __restrict__ gamma,
                                           const float* __restrict__ beta)
{
    int f = threadIdx.x;
    float inv_n = 1.0f / (float)N_NODES;
    float mean = sums[f] * inv_n;
    float var  = sums[64 + f] * inv_n - mean * mean;
    float sc   = gamma[f] * rsqrtf(var + BN_EPS);
    sums[128 + f] = sc;
    sums[192 + f] = beta[f] - mean * sc;
}

extern "C" __global__ __launch_bounds__(256)
void bn_apply_kernel(float* __restrict__ out, const float* __restrict__ sums)
{
    int j = blockIdx.x * 256 + threadIdx.x;   // float4 index
    int f0 = (j & 15) * 4;
    float4 sc = *(const float4*)&sums[128 + f0];
    float4 sh = *(const float4*)&sums[192 + f0];
    float4 v = ((float4*)out)[j];
    v.x = fmaf(v.x, sc.x, sh.x);
    v.y = fmaf(v.y, sc.y, sh.y);
    v.z = fmaf(v.z, sc.z, sh.z);
    v.w = fmaf(v.w, sc.w, sh.w);
    ((float4*)out)[j] = v;
}

extern "C" void kernel_launch(void* const* d_in, const int* in_sizes, int n_in,
                              void* d_out, int out_size, void* d_ws, size_t ws_size,
                              hipStream_t stream)
{
    const float* x     = (const float*)d_in[0];
    const int*   ei    = (const int*)  d_in[1];
    const float* ea    = (const float*)d_in[2];
    const float* We    = (const float*)d_in[3];
    const float* be    = (const float*)d_in[4];
    const float* W1    = (const float*)d_in[5];
    const float* b1    = (const float*)d_in[6];
    const float* W2    = (const float*)d_in[7];
    const float* b2    = (const float*)d_in[8];
    const float* gamma = (const float*)d_in[9];
    const float* beta  = (const float*)d_in[10];

    float* out = (float*)d_out;
    char*  wsb = (char*)d_ws;
    __half2* aggr2 = (__half2*)wsb;
    float*   sums  = (float*)(wsb + AGGR_BYTES);
    __half2* xh2   = (__half2*)(wsb + AGGR_BYTES + SUMS_BYTES);

    // zero aggr + BN sums (adjacent) in one memset
    hipMemsetAsync(wsb, 0, AGGR_BYTES + SUMS_BYTES, stream);

    prep_kernel<<<(N_NODES * DIM / 2) / 256, 256, 0, stream>>>(x, xh2);

    edge_kernel<<<(N_EDGES * 32) / 256, 256, 0, stream>>>(ei, ea, We, be, xh2, aggr2);

    node_kernel<<<(N_NODES + 63) / 64, 512, 0, stream>>>(
        x, aggr2, W1, b1, W2, b2, out, sums);

    bn_stats_kernel<<<1, 64, 0, stream>>>(sums, gamma, beta);

    bn_apply_kernel<<<(N_NODES * DIM / 4) / 256, 256, 0, stream>>>(out, sums);
}